// Round 17
// baseline (60.279 us; speedup 1.0000x reference)
//
#include <hip/hip_runtime.h>
#include <hip/hip_bf16.h>

#define HIDDEN 64
#define BATCH 2048
#define SFULL 1024
#define SM1 1023
#define ZSTR 1024                      // z' row stride (z'[b][sp])
#define LN_CLAMP -23.025850929940457f  // ln(1e-10)

typedef __bf16 bf16x8 __attribute__((ext_vector_type(8)));
typedef float  f32x4  __attribute__((ext_vector_type(4)));
typedef float  f32x16 __attribute__((ext_vector_type(16)));
typedef short  s16x2  __attribute__((ext_vector_type(2)));

// Fragment cache: 16 units of [64 lanes][16B] (R11-verified layout).
//  u 0,1   : a1[mt]   (b1 folded at k=3)
//  u 2..9  : a2[mt][c]  (u = 2 + mt*4 + c)
//  u 10..13: a3[c]
//  u 14,15 : a2b[mt]  bias frag (b2 at k_local=0)
#define FRAG_UNITS 16

// sigma mapping (hardware-verified R7-R15, absmax 0.0)
__device__ __forceinline__ int sig(int rg) {
    return 16 * ((rg >> 3) & 3) + 8 * ((rg >> 2) & 1) + (rg & 3) + 4 * (rg >> 5);
}

// truncating bf16 pack (RTZ) -- verified R9+
__device__ __forceinline__ unsigned pkt(float lo, float hi) {
    return __builtin_amdgcn_perm(__float_as_uint(hi), __float_as_uint(lo), 0x07060302u);
}
// packed relu on 2 bf16 -- verified R11+
__device__ __forceinline__ unsigned rp(unsigned x) {
    s16x2 v = __builtin_bit_cast(s16x2, x);
    s16x2 z = {0, 0};
    v = __builtin_elementwise_max(v, z);
    return __builtin_bit_cast(unsigned, v);
}

// pack+relu two f32x16 D-frags into 4 B-frags (layout verified R7)
__device__ __forceinline__ void relu_pack4(const f32x16 lo, const f32x16 hi, bf16x8* out) {
#pragma unroll
    for (int c = 0; c < 4; ++c) {
        union { unsigned u[4]; bf16x8 v; } r;
        r.u[0] = rp(pkt(lo[4 * c + 0], lo[4 * c + 1]));
        r.u[1] = rp(pkt(lo[4 * c + 2], lo[4 * c + 3]));
        r.u[2] = rp(pkt(hi[4 * c + 0], hi[4 * c + 1]));
        r.u[3] = rp(pkt(hi[4 * c + 2], hi[4 * c + 3]));
        out[c] = r.v;
    }
}

// feature B-frag {xt, t, x0, 1, ...}
__device__ __forceinline__ bf16x8 featpk(float xt, float t, float x0) {
    union { unsigned u[4]; bf16x8 v; } r;
    r.u[0] = pkt(xt, t);
    r.u[1] = pkt(x0, 1.0f);
    r.u[2] = r.u[0]; r.u[3] = r.u[1];
    return r.v;
}

// ---------------- Kernel 0: one-time fragment gather (1 block) -------------
__global__ __launch_bounds__(256) void frag_setup_kernel(
    const float* __restrict__ W1, const float* __restrict__ b1,
    const float* __restrict__ W2, const float* __restrict__ b2,
    const float* __restrict__ Wout, char* __restrict__ F)
{
    const int l    = threadIdx.x & 63;
    const int wv   = threadIdx.x >> 6;
    const int pcol = l & 31;
    const int hi   = l >> 5;

    if (wv == 0) {
#pragma unroll
        for (int mt = 0; mt < 2; ++mt) {
            const int hout = sig(32 * mt + pcol);
            bf16x8 v;
#pragma unroll
            for (int j = 0; j < 8; ++j) {
                const int k = 8 * hi + j;
                v[j] = (k < 3) ? (__bf16)W1[k * 64 + hout]
                     : (k == 3) ? (__bf16)b1[hout] : (__bf16)0.0f;
            }
            *(bf16x8*)(F + ((mt * 64 + l) << 4)) = v;
        }
#pragma unroll
        for (int c = 0; c < 4; ++c) {
            bf16x8 v;
#pragma unroll
            for (int j = 0; j < 8; ++j) {
                const int k = 16 * c + 8 * hi + j;
                v[j] = (pcol < 3) ? (__bf16)Wout[k * 3 + pcol] : (__bf16)0.0f;
            }
            *(bf16x8*)(F + (((10 + c) * 64 + l) << 4)) = v;
        }
    } else if (wv == 1 || wv == 2) {
        const int mt = wv - 1;
        const int hout = sig(32 * mt + pcol);
#pragma unroll
        for (int c = 0; c < 4; ++c) {
            bf16x8 v;
#pragma unroll
            for (int j = 0; j < 8; ++j)
                v[j] = (__bf16)W2[(16 * c + 8 * hi + j) * 64 + hout];
            *(bf16x8*)(F + (((2 + mt * 4 + c) * 64 + l) << 4)) = v;
        }
    } else {
#pragma unroll
        for (int mt = 0; mt < 2; ++mt) {
            const int hout = sig(32 * mt + pcol);
            bf16x8 v;
#pragma unroll
            for (int j = 0; j < 8; ++j)
                v[j] = (hi == 0 && j == 0) ? (__bf16)b2[hout] : (__bf16)0.0f;
            *(bf16x8*)(F + (((14 + mt) * 64 + l) << 4)) = v;
        }
    }
}

// ---------------- Kernel 1: R11 chain, lane = sp (coalesced I/O) -----------
// grid (64, 32), block 256 (4 waves). Wave owns 32 CONSECUTIVE sp values
// (sp = blockIdx.y*32 + (lane&31)) for ONE b per iteration, looping 8 b's
// (b = blockIdx.x*32 + wv*8 + i). Loads rowp[pcol], rowp[pcol+1]: 256B
// contiguous (4-8 cachelines/wave vs 64 with lane=b). Store z'[b][sp]:
// 128B contiguous. MFMA chain identical to R11 (hardware-verified).
__global__ __launch_bounds__(256, 3) void mlp_z_kernel(
    const float* __restrict__ ys,    // (B, S, 2)
    const char* __restrict__ F,      // fragment cache
    const float* __restrict__ bout,  // (3)
    float* __restrict__ zp)          // z' (BATCH, ZSTR)
{
    const int l    = threadIdx.x & 63;
    const int wv   = threadIdx.x >> 6;
    const int pcol = l & 31;
    const int hi   = l >> 5;

    const int b0   = blockIdx.x * 32 + wv * 8;
    const int spt0 = blockIdx.y * 32;
    const int sp   = spt0 + pcol;                 // this lane's point
    const int o1   = min(pcol + 1, SM1 - spt0);   // clamped neighbor offset

    // ---- coalesced fragment loads (L2-hot), R11 layout ----
    bf16x8 a1[2], a2[2][4], a3[4], a2b[2];
#pragma unroll
    for (int mt = 0; mt < 2; ++mt) {
        a1[mt]  = *(const bf16x8*)(F + ((mt * 64 + l) << 4));
        a2b[mt] = *(const bf16x8*)(F + (((14 + mt) * 64 + l) << 4));
#pragma unroll
        for (int c = 0; c < 4; ++c)
            a2[mt][c] = *(const bf16x8*)(F + (((2 + mt * 4 + c) * 64 + l) << 4));
    }
#pragma unroll
    for (int c = 0; c < 4; ++c)
        a3[c] = *(const bf16x8*)(F + (((10 + c) * 64 + l) << 4));

    bf16x8 Bone;
    {
        union { unsigned u[4]; bf16x8 v; } r;
        r.u[0] = (hi == 0) ? 0x3F80u : 0u;  // bf16(1.0)
        r.u[1] = 0u; r.u[2] = 0u; r.u[3] = 0u;
        Bone = r.v;
    }

    const float bo0 = bout[0], bo1 = bout[1], bo2 = bout[2];

    f32x16 zero16;
#pragma unroll
    for (int i = 0; i < 16; ++i) zero16[i] = 0.0f;

    const float2* rowp = reinterpret_cast<const float2*>(ys) + (size_t)b0 * SFULL + spt0;
    float* zrow = zp + (size_t)b0 * ZSTR + spt0 + pcol;

    float2 q0 = rowp[pcol];
    float2 q1 = rowp[o1];

    const bool do_store = (l < 32) && (sp < SM1);

    for (int i = 0; i < 8; ++i) {
        // prefetch next row's inputs (coalesced)
        const float2* nrowp = rowp + SFULL;
        float2 n0, n1;
        if (i < 7) { n0 = nrowp[pcol]; n1 = nrowp[o1]; }

        const float x0 = q0.y, t = q1.x, xt = q1.y;
        const bf16x8 f0 = featpk(xt, t, x0);

        // ---- layer 1 (b1 folded) ----
        f32x16 acc1_0 = __builtin_amdgcn_mfma_f32_32x32x16_bf16(a1[0], f0, zero16, 0, 0, 0);
        f32x16 acc1_1 = __builtin_amdgcn_mfma_f32_32x32x16_bf16(a1[1], f0, zero16, 0, 0, 0);

        bf16x8 h1f[4];
        relu_pack4(acc1_0, acc1_1, h1f);

        // bias MFMAs start the L2 accumulators
        f32x16 acc2_0 = __builtin_amdgcn_mfma_f32_32x32x16_bf16(a2b[0], Bone, zero16, 0, 0, 0);
        f32x16 acc2_1 = __builtin_amdgcn_mfma_f32_32x32x16_bf16(a2b[1], Bone, zero16, 0, 0, 0);

        // ---- layer 2 ----
#pragma unroll
        for (int c = 0; c < 4; ++c) {
            acc2_0 = __builtin_amdgcn_mfma_f32_32x32x16_bf16(a2[0][c], h1f[c], acc2_0, 0, 0, 0);
            acc2_1 = __builtin_amdgcn_mfma_f32_32x32x16_bf16(a2[1][c], h1f[c], acc2_1, 0, 0, 0);
        }

        bf16x8 h2f[4];
        relu_pack4(acc2_0, acc2_1, h2f);

        // ---- layer 3 (serial 4; only rows 0..2 consumed) ----
        f32x16 acc3 = __builtin_amdgcn_mfma_f32_32x32x16_bf16(a3[0], h2f[0], zero16, 0, 0, 0);
#pragma unroll
        for (int c = 1; c < 4; ++c)
            acc3 = __builtin_amdgcn_mfma_f32_32x32x16_bf16(a3[c], h2f[c], acc3, 0, 0, 0);

        // epilogue (hi=0 lanes hold rows 0..2)
        const float c0 = acc3[0] + bo0;
        const float c1 = acc3[1] + bo1;
        const float c2 = acc3[2] + bo2;
        const float zv = fmaf(c2, fmaf(4.0f * xt, xt, -2.0f), fmaf(c1, xt + xt, c0));

        if (do_store) zrow[0] = zv;     // 128B contiguous per wave
        zrow += ZSTR;
        rowp = nrowp;
        if (i < 7) { q0 = n0; q1 = n1; }
    }
}

// ---------------- reduction helpers ----------------
__device__ __forceinline__ float blk_reduce_max(float v) {
    __shared__ float s[4];
#pragma unroll
    for (int off = 32; off >= 1; off >>= 1) v = fmaxf(v, __shfl_xor(v, off));
    if ((threadIdx.x & 63) == 0) s[threadIdx.x >> 6] = v;
    __syncthreads();
    v = fmaxf(fmaxf(s[0], s[1]), fmaxf(s[2], s[3]));
    __syncthreads();
    return v;
}

__device__ __forceinline__ float blk_reduce_sum(float v) {
    __shared__ float s[4];
#pragma unroll
    for (int off = 32; off >= 1; off >>= 1) v += __shfl_xor(v, off);
    if ((threadIdx.x & 63) == 0) s[threadIdx.x >> 6] = v;
    __syncthreads();
    v = (s[0] + s[1]) + (s[2] + s[3]);
    __syncthreads();
    return v;
}

// ---------------- Kernel 2: per-column softmax + logclip sum ----------------
// Column sp of z' is strided (4KB); z' is L2-resident (8.4MB) so the
// gather runs at L2 bandwidth. Single read pass (vals cached in regs).
__global__ __launch_bounds__(256) void col_softmax_kernel(
    const float* __restrict__ zp, float* __restrict__ colsum)
{
    const int sp = blockIdx.x;
    const int tid = threadIdx.x;
    const float* col = zp + sp;

    float vals[8];
    float m = -3.4e38f;
#pragma unroll
    for (int i = 0; i < 8; ++i) {
        vals[i] = col[(size_t)(tid + 256 * i) * ZSTR];
        m = fmaxf(m, vals[i]);
    }
    const float M = blk_reduce_max(m);

    float se = 0.0f;
#pragma unroll
    for (int i = 0; i < 8; ++i) se += __expf(vals[i] - M);
    const float S = blk_reduce_sum(se);
    const float L = __logf(S);

    float acc = 0.0f;
#pragma unroll
    for (int i = 0; i < 8; ++i) acc += fmaxf(vals[i] - M - L, LN_CLAMP);
    const float T = blk_reduce_sum(acc);
    if (tid == 0) colsum[sp] = T;
}

// ---------------- Kernel 3: final scalar ----------------
__global__ __launch_bounds__(256) void final_reduce_kernel(
    const float* __restrict__ colsum, float* __restrict__ out)
{
    const int tid = threadIdx.x;
    float v = 0.0f;
    for (int i = tid; i < SM1; i += 256) v += colsum[i];
    const float T = blk_reduce_sum(v);
    if (tid == 0) out[0] = T / (float)BATCH;
}

extern "C" void kernel_launch(void* const* d_in, const int* in_sizes, int n_in,
                              void* d_out, int out_size, void* d_ws, size_t ws_size,
                              hipStream_t stream) {
    const float* ys   = (const float*)d_in[0];
    const float* W1   = (const float*)d_in[1];
    const float* b1   = (const float*)d_in[2];
    const float* W2   = (const float*)d_in[3];
    const float* b2   = (const float*)d_in[4];
    const float* Wout = (const float*)d_in[5];
    const float* bout = (const float*)d_in[6];
    float* out = (float*)d_out;

    float* zp     = (float*)d_ws;                         // BATCH*ZSTR floats
    float* colsum = zp + (size_t)BATCH * ZSTR;            // SM1 floats
    size_t fo = ((size_t)BATCH * ZSTR + SM1) * sizeof(float);
    fo = (fo + 15) & ~(size_t)15;
    char* F = (char*)d_ws + fo;                           // 16*64*16 = 16 KB

    frag_setup_kernel<<<1, 256, 0, stream>>>(W1, b1, W2, b2, Wout, F);
    dim3 grid1(64, 32);  // 64*32 b x 32*32 sp tiles
    mlp_z_kernel<<<grid1, 256, 0, stream>>>(ys, F, bout, zp);
    col_softmax_kernel<<<SM1, 256, 0, stream>>>(zp, colsum);
    final_reduce_kernel<<<1, 256, 0, stream>>>(colsum, out);
}

// Round 18
// 55.619 us; speedup vs baseline: 1.0838x; 1.0838x over previous
//
#include <hip/hip_runtime.h>
#include <hip/hip_bf16.h>

#define HIDDEN 64
#define BATCH 2048
#define SFULL 1024
#define SM1 1023
#define LN_CLAMP -23.025850929940457f  // ln(1e-10)
#define SP_PER 16                      // grid.y = 64 -> 64*16 = 1024 sp slots

typedef __bf16 bf16x8 __attribute__((ext_vector_type(8)));
typedef float  f32x4  __attribute__((ext_vector_type(4)));
typedef float  f32x16 __attribute__((ext_vector_type(16)));
typedef short  s16x2  __attribute__((ext_vector_type(2)));

// Fragment cache: 16 units of [64 lanes][16B] (R11-verified layout).
//  u 0,1   : a1[mt]     (b1 folded at k=3)
//  u 2..9  : a2[mt][c]  (u = 2 + mt*4 + c)
//  u 10..13: a3[c]
//  u 14,15 : a2b[mt]    bias frag (b2 at k_local=0)
#define FRAG_UNITS 16

// sigma mapping (hardware-verified R7-R16, absmax 0.0)
__device__ __forceinline__ int sig(int rg) {
    return 16 * ((rg >> 3) & 3) + 8 * ((rg >> 2) & 1) + (rg & 3) + 4 * (rg >> 5);
}

// truncating bf16 pack (RTZ) -- verified R9+
__device__ __forceinline__ unsigned pkt(float lo, float hi) {
    return __builtin_amdgcn_perm(__float_as_uint(hi), __float_as_uint(lo), 0x07060302u);
}
// packed relu on 2 bf16 -- verified R11+
__device__ __forceinline__ unsigned rp(unsigned x) {
    s16x2 v = __builtin_bit_cast(s16x2, x);
    s16x2 z = {0, 0};
    v = __builtin_elementwise_max(v, z);
    return __builtin_bit_cast(unsigned, v);
}

// pack+relu two f32x16 D-frags into 4 B-frags (layout verified R7)
__device__ __forceinline__ void relu_pack4(const f32x16 lo, const f32x16 hi, bf16x8* out) {
#pragma unroll
    for (int c = 0; c < 4; ++c) {
        union { unsigned u[4]; bf16x8 v; } r;
        r.u[0] = rp(pkt(lo[4 * c + 0], lo[4 * c + 1]));
        r.u[1] = rp(pkt(lo[4 * c + 2], lo[4 * c + 3]));
        r.u[2] = rp(pkt(hi[4 * c + 0], hi[4 * c + 1]));
        r.u[3] = rp(pkt(hi[4 * c + 2], hi[4 * c + 3]));
        out[c] = r.v;
    }
}

// feature B-frag {xt, t, x0, 1, ...} (elems k>=4 multiply A=0)
__device__ __forceinline__ bf16x8 featpk(float xt, float t, float x0) {
    union { unsigned u[4]; bf16x8 v; } r;
    r.u[0] = pkt(xt, t);
    r.u[1] = pkt(x0, 1.0f);
    r.u[2] = r.u[0]; r.u[3] = r.u[1];
    return r.v;
}

// ---------------- Kernel 0: fragment gather, 16 blocks (1 unit each) -------
// Same math as R11's setup (hardware-verified), parallelized across blocks
// so the scattered-load latency chains run concurrently (~0.3us vs ~2us).
__global__ __launch_bounds__(64) void frag_setup_kernel(
    const float* __restrict__ W1, const float* __restrict__ b1,
    const float* __restrict__ W2, const float* __restrict__ b2,
    const float* __restrict__ Wout, char* __restrict__ F)
{
    const int l    = threadIdx.x;    // 0..63
    const int u    = blockIdx.x;     // unit 0..15
    const int pcol = l & 31;
    const int hi   = l >> 5;

    bf16x8 v;
    if (u < 2) {
        // a1[mt]: A[row=pcol][k=8hi+j] = W1aug[k][sig(32mt+pcol)]
        const int hout = sig(32 * u + pcol);
#pragma unroll
        for (int j = 0; j < 8; ++j) {
            const int k = 8 * hi + j;
            v[j] = (k < 3) ? (__bf16)W1[k * 64 + hout]
                 : (k == 3) ? (__bf16)b1[hout] : (__bf16)0.0f;
        }
    } else if (u < 10) {
        // a2[mt][c]: A[row=pcol][k=16c+8hi+j] = W2[k][sig(32mt+pcol)]
        const int mt = (u - 2) >> 2;
        const int c  = (u - 2) & 3;
        const int hout = sig(32 * mt + pcol);
#pragma unroll
        for (int j = 0; j < 8; ++j)
            v[j] = (__bf16)W2[(16 * c + 8 * hi + j) * 64 + hout];
    } else if (u < 14) {
        // a3[c]: A[row=pcol][k=16c+8hi+j] = (pcol<3)? Wout[k][pcol] : 0
        const int c = u - 10;
#pragma unroll
        for (int j = 0; j < 8; ++j) {
            const int k = 16 * c + 8 * hi + j;
            v[j] = (pcol < 3) ? (__bf16)Wout[k * 3 + pcol] : (__bf16)0.0f;
        }
    } else {
        // a2b[mt]: bias frag; only k_local==0 (hi==0, j==0) nonzero
        const int mt = u - 14;
        const int hout = sig(32 * mt + pcol);
#pragma unroll
        for (int j = 0; j < 8; ++j)
            v[j] = (hi == 0 && j == 0) ? (__bf16)b2[hout] : (__bf16)0.0f;
    }
    *(bf16x8*)(F + ((u * 64 + l) << 4)) = v;
}

// ---------------- Kernel 1: 3-layer MLP, 32x32x16 MFMA (R11-exact) --------
// grid (16, 64), block 256 (4 waves), __launch_bounds__(256,3).
// Wave owns 32 points b = (blockIdx.x*4+wv)*32 + (lane&31); 16 sp iterations.
// Per sp (16 MFMA): L1 2 -> pack -> L2 2 bias + 2x4 chain -> pack ->
// L3 serial 4 -> epilogue rows 0..2 (hi=0 lanes) -> store z[sp][b].
__global__ __launch_bounds__(256, 3) void mlp_z_kernel(
    const float* __restrict__ ys,    // (B, S, 2)
    const char* __restrict__ F,      // fragment cache
    const float* __restrict__ bout,  // (3)
    float* __restrict__ z)           // (SM1, BATCH)
{
    const int l    = threadIdx.x & 63;
    const int wv   = threadIdx.x >> 6;
    const int pcol = l & 31;
    const int hi   = l >> 5;

    const int b   = (blockIdx.x * 4 + wv) * 32 + pcol;
    const int sp0 = blockIdx.y * SP_PER;
    const int omax = (SFULL - 1) - sp0;

    // ---- coalesced fragment loads (L2-hot) ----
    bf16x8 a1[2], a2[2][4], a3[4], a2b[2];
#pragma unroll
    for (int mt = 0; mt < 2; ++mt) {
        a1[mt]  = *(const bf16x8*)(F + ((mt * 64 + l) << 4));
        a2b[mt] = *(const bf16x8*)(F + (((14 + mt) * 64 + l) << 4));
#pragma unroll
        for (int c = 0; c < 4; ++c)
            a2[mt][c] = *(const bf16x8*)(F + (((2 + mt * 4 + c) * 64 + l) << 4));
    }
#pragma unroll
    for (int c = 0; c < 4; ++c)
        a3[c] = *(const bf16x8*)(F + (((10 + c) * 64 + l) << 4));

    // B_one: B[k_local][*] = 1 at k_local==0 -> hi==0 lanes, halfword 0
    bf16x8 Bone;
    {
        union { unsigned u[4]; bf16x8 v; } r;
        r.u[0] = (hi == 0) ? 0x3F80u : 0u;  // bf16(1.0)
        r.u[1] = 0u; r.u[2] = 0u; r.u[3] = 0u;
        Bone = r.v;
    }

    const float bo0 = bout[0], bo1 = bout[1], bo2 = bout[2];

    f32x16 zero16;
#pragma unroll
    for (int i = 0; i < 16; ++i) zero16[i] = 0.0f;

    const float2* base2 = reinterpret_cast<const float2*>(ys) + ((size_t)b * SFULL + sp0);
    float* zb = z + (size_t)sp0 * BATCH + b;

    float2 q0 = base2[0];
    float2 q1 = base2[min(1, omax)];
    float2 qn = base2[min(2, omax)];

    for (int it = 0; it < SP_PER; ++it) {
        const float2 qn2 = base2[min(it + 3, omax)];  // prefetch

        const float x0 = q0.y, t = q1.x, xt = q1.y;
        const bf16x8 f0 = featpk(xt, t, x0);

        // ---- layer 1 (b1 folded) ----
        f32x16 acc1_0 = __builtin_amdgcn_mfma_f32_32x32x16_bf16(a1[0], f0, zero16, 0, 0, 0);
        f32x16 acc1_1 = __builtin_amdgcn_mfma_f32_32x32x16_bf16(a1[1], f0, zero16, 0, 0, 0);

        // L2 bias mfmas: independent of h1, hide under L1/pack
        f32x16 acc2_0 = __builtin_amdgcn_mfma_f32_32x32x16_bf16(a2b[0], Bone, zero16, 0, 0, 0);
        f32x16 acc2_1 = __builtin_amdgcn_mfma_f32_32x32x16_bf16(a2b[1], Bone, zero16, 0, 0, 0);

        bf16x8 h1f[4];
        relu_pack4(acc1_0, acc1_1, h1f);

        // ---- layer 2 ----
#pragma unroll
        for (int c = 0; c < 4; ++c) {
            acc2_0 = __builtin_amdgcn_mfma_f32_32x32x16_bf16(a2[0][c], h1f[c], acc2_0, 0, 0, 0);
            acc2_1 = __builtin_amdgcn_mfma_f32_32x32x16_bf16(a2[1][c], h1f[c], acc2_1, 0, 0, 0);
        }

        bf16x8 h2f[4];
        relu_pack4(acc2_0, acc2_1, h2f);

        // ---- layer 3 (serial 4; only rows 0..2 consumed) ----
        f32x16 acc3 = __builtin_amdgcn_mfma_f32_32x32x16_bf16(a3[0], h2f[0], zero16, 0, 0, 0);
#pragma unroll
        for (int c = 1; c < 4; ++c)
            acc3 = __builtin_amdgcn_mfma_f32_32x32x16_bf16(a3[c], h2f[c], acc3, 0, 0, 0);

        // epilogue (hi=0 lanes hold rows 0..2)
        const float c0 = acc3[0] + bo0;
        const float c1 = acc3[1] + bo1;
        const float c2 = acc3[2] + bo2;
        const float zv = fmaf(c2, fmaf(4.0f * xt, xt, -2.0f), fmaf(c1, xt + xt, c0));

        if (l < 32 && sp0 + it < SM1)
            zb[(size_t)it * BATCH] = zv;

        q0 = q1; q1 = qn; qn = qn2;
    }
}

// ---------------- reduction helpers ----------------
__device__ __forceinline__ float blk_reduce_max(float v) {
    __shared__ float s[4];
#pragma unroll
    for (int off = 32; off >= 1; off >>= 1) v = fmaxf(v, __shfl_xor(v, off));
    if ((threadIdx.x & 63) == 0) s[threadIdx.x >> 6] = v;
    __syncthreads();
    v = fmaxf(fmaxf(s[0], s[1]), fmaxf(s[2], s[3]));
    __syncthreads();
    return v;
}

__device__ __forceinline__ float blk_reduce_sum(float v) {
    __shared__ float s[4];
#pragma unroll
    for (int off = 32; off >= 1; off >>= 1) v += __shfl_xor(v, off);
    if ((threadIdx.x & 63) == 0) s[threadIdx.x >> 6] = v;
    __syncthreads();
    v = (s[0] + s[1]) + (s[2] + s[3]);
    __syncthreads();
    return v;
}

// ---------------- Kernel 2: per-column softmax + logclip sum + final -------
// z[sp][0..2047] is contiguous (coalesced). Final mean fused via atomicAdd
// (out zeroed by hipMemsetAsync in kernel_launch; FP-atomic ordering noise
// ~1e-3, far under threshold).
__global__ __launch_bounds__(256) void col_softmax_kernel(
    const float* __restrict__ z, float* __restrict__ out)
{
    const int sp = blockIdx.x;
    const int tid = threadIdx.x;
    const float* col = z + (size_t)sp * BATCH;

    float vals[8];
    float m = -3.4e38f;
#pragma unroll
    for (int i = 0; i < 8; ++i) {
        vals[i] = col[tid + 256 * i];
        m = fmaxf(m, vals[i]);
    }
    const float M = blk_reduce_max(m);

    float se = 0.0f;
#pragma unroll
    for (int i = 0; i < 8; ++i) se += __expf(vals[i] - M);
    const float S = blk_reduce_sum(se);
    const float L = __logf(S);

    float acc = 0.0f;
#pragma unroll
    for (int i = 0; i < 8; ++i) acc += fmaxf(vals[i] - M - L, LN_CLAMP);
    const float T = blk_reduce_sum(acc);
    if (tid == 0) atomicAdd(out, T * (1.0f / (float)BATCH));
}

extern "C" void kernel_launch(void* const* d_in, const int* in_sizes, int n_in,
                              void* d_out, int out_size, void* d_ws, size_t ws_size,
                              hipStream_t stream) {
    const float* ys   = (const float*)d_in[0];
    const float* W1   = (const float*)d_in[1];
    const float* b1   = (const float*)d_in[2];
    const float* W2   = (const float*)d_in[3];
    const float* b2   = (const float*)d_in[4];
    const float* Wout = (const float*)d_in[5];
    const float* bout = (const float*)d_in[6];
    float* out = (float*)d_out;

    float* z = (float*)d_ws;                              // SM1*BATCH floats
    size_t fo = (size_t)SM1 * BATCH * sizeof(float);
    fo = (fo + 15) & ~(size_t)15;
    char* F = (char*)d_ws + fo;                           // 16*64*16 = 16 KB

    hipMemsetAsync(out, 0, sizeof(float), stream);        // capture-safe
    frag_setup_kernel<<<FRAG_UNITS, 64, 0, stream>>>(W1, b1, W2, b2, Wout, F);
    dim3 grid1(16, 64);  // 16*4 waves * 32 pts = 2048 b ; 64*16 = 1024 sp slots
    mlp_z_kernel<<<grid1, 256, 0, stream>>>(ys, F, bout, z);
    col_softmax_kernel<<<SM1, 256, 0, stream>>>(z, out);
}

// Round 19
// 42.190 us; speedup vs baseline: 1.4288x; 1.3183x over previous
//
#include <hip/hip_runtime.h>
#include <hip/hip_bf16.h>

#define HIDDEN 64
#define BATCH 2048
#define SFULL 1024
#define SM1 1023
#define LN_CLAMP -23.025850929940457f  // ln(1e-10)
#define SP_PER 16                      // grid.y = 64 -> 64*16 = 1024 sp slots

typedef __bf16 bf16x8 __attribute__((ext_vector_type(8)));
typedef float  f32x4  __attribute__((ext_vector_type(4)));
typedef float  f32x16 __attribute__((ext_vector_type(16)));
typedef short  s16x2  __attribute__((ext_vector_type(2)));

// Fragment cache: 16 units of [64 lanes][16B] (R11-verified layout).
//  u 0,1   : a1[mt]     (b1 folded at k=3)
//  u 2..9  : a2[mt][c]  (u = 2 + mt*4 + c)
//  u 10..13: a3[c]
//  u 14,15 : a2b[mt]    bias frag (b2 at k_local=0)
#define FRAG_UNITS 16

// sigma mapping (hardware-verified R7-R17, absmax 0.0)
__device__ __forceinline__ int sig(int rg) {
    return 16 * ((rg >> 3) & 3) + 8 * ((rg >> 2) & 1) + (rg & 3) + 4 * (rg >> 5);
}

// truncating bf16 pack (RTZ) -- verified R9+
__device__ __forceinline__ unsigned pkt(float lo, float hi) {
    return __builtin_amdgcn_perm(__float_as_uint(hi), __float_as_uint(lo), 0x07060302u);
}
// packed relu on 2 bf16 -- verified R11+
__device__ __forceinline__ unsigned rp(unsigned x) {
    s16x2 v = __builtin_bit_cast(s16x2, x);
    s16x2 z = {0, 0};
    v = __builtin_elementwise_max(v, z);
    return __builtin_bit_cast(unsigned, v);
}

// pack+relu two f32x16 D-frags into 4 B-frags (layout verified R7)
__device__ __forceinline__ void relu_pack4(const f32x16 lo, const f32x16 hi, bf16x8* out) {
#pragma unroll
    for (int c = 0; c < 4; ++c) {
        union { unsigned u[4]; bf16x8 v; } r;
        r.u[0] = rp(pkt(lo[4 * c + 0], lo[4 * c + 1]));
        r.u[1] = rp(pkt(lo[4 * c + 2], lo[4 * c + 3]));
        r.u[2] = rp(pkt(hi[4 * c + 0], hi[4 * c + 1]));
        r.u[3] = rp(pkt(hi[4 * c + 2], hi[4 * c + 3]));
        out[c] = r.v;
    }
}

// feature B-frag {xt, t, x0, 1, ...} (elems k>=4 multiply A=0)
__device__ __forceinline__ bf16x8 featpk(float xt, float t, float x0) {
    union { unsigned u[4]; bf16x8 v; } r;
    r.u[0] = pkt(xt, t);
    r.u[1] = pkt(x0, 1.0f);
    r.u[2] = r.u[0]; r.u[3] = r.u[1];
    return r.v;
}

// ---------------- Kernel 0: fragment gather, 16 blocks (1 unit each) -------
// Same math as R11's setup (hardware-verified); block-parallel so the
// scattered-load latency chains run concurrently.
__global__ __launch_bounds__(64) void frag_setup_kernel(
    const float* __restrict__ W1, const float* __restrict__ b1,
    const float* __restrict__ W2, const float* __restrict__ b2,
    const float* __restrict__ Wout, char* __restrict__ F)
{
    const int l    = threadIdx.x;    // 0..63
    const int u    = blockIdx.x;     // unit 0..15
    const int pcol = l & 31;
    const int hi   = l >> 5;

    bf16x8 v;
    if (u < 2) {
        const int hout = sig(32 * u + pcol);
#pragma unroll
        for (int j = 0; j < 8; ++j) {
            const int k = 8 * hi + j;
            v[j] = (k < 3) ? (__bf16)W1[k * 64 + hout]
                 : (k == 3) ? (__bf16)b1[hout] : (__bf16)0.0f;
        }
    } else if (u < 10) {
        const int mt = (u - 2) >> 2;
        const int c  = (u - 2) & 3;
        const int hout = sig(32 * mt + pcol);
#pragma unroll
        for (int j = 0; j < 8; ++j)
            v[j] = (__bf16)W2[(16 * c + 8 * hi + j) * 64 + hout];
    } else if (u < 14) {
        const int c = u - 10;
#pragma unroll
        for (int j = 0; j < 8; ++j) {
            const int k = 16 * c + 8 * hi + j;
            v[j] = (pcol < 3) ? (__bf16)Wout[k * 3 + pcol] : (__bf16)0.0f;
        }
    } else {
        const int mt = u - 14;
        const int hout = sig(32 * mt + pcol);
#pragma unroll
        for (int j = 0; j < 8; ++j)
            v[j] = (hi == 0 && j == 0) ? (__bf16)b2[hout] : (__bf16)0.0f;
    }
    *(bf16x8*)(F + ((u * 64 + l) << 4)) = v;
}

// ---------------- Kernel 1: 3-layer MLP, 32x32x16 MFMA (R11-exact) --------
// grid (16, 64), block 256 (4 waves), __launch_bounds__(256,3).
// Wave owns 32 points b = (blockIdx.x*4+wv)*32 + (lane&31); 16 sp iterations.
// Per sp (16 MFMA): L1 2 -> pack -> L2 2 bias + 2x4 chain -> pack ->
// L3 serial 4 -> epilogue rows 0..2 (hi=0 lanes) -> store z[sp][b].
__global__ __launch_bounds__(256, 3) void mlp_z_kernel(
    const float* __restrict__ ys,    // (B, S, 2)
    const char* __restrict__ F,      // fragment cache
    const float* __restrict__ bout,  // (3)
    float* __restrict__ z)           // (SM1, BATCH)
{
    const int l    = threadIdx.x & 63;
    const int wv   = threadIdx.x >> 6;
    const int pcol = l & 31;
    const int hi   = l >> 5;

    const int b   = (blockIdx.x * 4 + wv) * 32 + pcol;
    const int sp0 = blockIdx.y * SP_PER;
    const int omax = (SFULL - 1) - sp0;

    // ---- coalesced fragment loads (L2-hot) ----
    bf16x8 a1[2], a2[2][4], a3[4], a2b[2];
#pragma unroll
    for (int mt = 0; mt < 2; ++mt) {
        a1[mt]  = *(const bf16x8*)(F + ((mt * 64 + l) << 4));
        a2b[mt] = *(const bf16x8*)(F + (((14 + mt) * 64 + l) << 4));
#pragma unroll
        for (int c = 0; c < 4; ++c)
            a2[mt][c] = *(const bf16x8*)(F + (((2 + mt * 4 + c) * 64 + l) << 4));
    }
#pragma unroll
    for (int c = 0; c < 4; ++c)
        a3[c] = *(const bf16x8*)(F + (((10 + c) * 64 + l) << 4));

    // B_one: B[k_local][*] = 1 at k_local==0 -> hi==0 lanes, halfword 0
    bf16x8 Bone;
    {
        union { unsigned u[4]; bf16x8 v; } r;
        r.u[0] = (hi == 0) ? 0x3F80u : 0u;  // bf16(1.0)
        r.u[1] = 0u; r.u[2] = 0u; r.u[3] = 0u;
        Bone = r.v;
    }

    const float bo0 = bout[0], bo1 = bout[1], bo2 = bout[2];

    f32x16 zero16;
#pragma unroll
    for (int i = 0; i < 16; ++i) zero16[i] = 0.0f;

    const float2* base2 = reinterpret_cast<const float2*>(ys) + ((size_t)b * SFULL + sp0);
    float* zb = z + (size_t)sp0 * BATCH + b;

    float2 q0 = base2[0];
    float2 q1 = base2[min(1, omax)];
    float2 qn = base2[min(2, omax)];

    for (int it = 0; it < SP_PER; ++it) {
        const float2 qn2 = base2[min(it + 3, omax)];  // prefetch

        const float x0 = q0.y, t = q1.x, xt = q1.y;
        const bf16x8 f0 = featpk(xt, t, x0);

        // ---- layer 1 (b1 folded) ----
        f32x16 acc1_0 = __builtin_amdgcn_mfma_f32_32x32x16_bf16(a1[0], f0, zero16, 0, 0, 0);
        f32x16 acc1_1 = __builtin_amdgcn_mfma_f32_32x32x16_bf16(a1[1], f0, zero16, 0, 0, 0);

        // L2 bias mfmas: independent of h1, hide under L1/pack
        f32x16 acc2_0 = __builtin_amdgcn_mfma_f32_32x32x16_bf16(a2b[0], Bone, zero16, 0, 0, 0);
        f32x16 acc2_1 = __builtin_amdgcn_mfma_f32_32x32x16_bf16(a2b[1], Bone, zero16, 0, 0, 0);

        bf16x8 h1f[4];
        relu_pack4(acc1_0, acc1_1, h1f);

        // ---- layer 2 ----
#pragma unroll
        for (int c = 0; c < 4; ++c) {
            acc2_0 = __builtin_amdgcn_mfma_f32_32x32x16_bf16(a2[0][c], h1f[c], acc2_0, 0, 0, 0);
            acc2_1 = __builtin_amdgcn_mfma_f32_32x32x16_bf16(a2[1][c], h1f[c], acc2_1, 0, 0, 0);
        }

        bf16x8 h2f[4];
        relu_pack4(acc2_0, acc2_1, h2f);

        // ---- layer 3 (serial 4; only rows 0..2 consumed) ----
        f32x16 acc3 = __builtin_amdgcn_mfma_f32_32x32x16_bf16(a3[0], h2f[0], zero16, 0, 0, 0);
#pragma unroll
        for (int c = 1; c < 4; ++c)
            acc3 = __builtin_amdgcn_mfma_f32_32x32x16_bf16(a3[c], h2f[c], acc3, 0, 0, 0);

        // epilogue (hi=0 lanes hold rows 0..2)
        const float c0 = acc3[0] + bo0;
        const float c1 = acc3[1] + bo1;
        const float c2 = acc3[2] + bo2;
        const float zv = fmaf(c2, fmaf(4.0f * xt, xt, -2.0f), fmaf(c1, xt + xt, c0));

        if (l < 32 && sp0 + it < SM1)
            zb[(size_t)it * BATCH] = zv;

        q0 = q1; q1 = qn; qn = qn2;
    }
}

// ---------------- reduction helpers ----------------
__device__ __forceinline__ float blk_reduce_max(float v) {
    __shared__ float s[4];
#pragma unroll
    for (int off = 32; off >= 1; off >>= 1) v = fmaxf(v, __shfl_xor(v, off));
    if ((threadIdx.x & 63) == 0) s[threadIdx.x >> 6] = v;
    __syncthreads();
    v = fmaxf(fmaxf(s[0], s[1]), fmaxf(s[2], s[3]));
    __syncthreads();
    return v;
}

__device__ __forceinline__ float blk_reduce_sum(float v) {
    __shared__ float s[4];
#pragma unroll
    for (int off = 32; off >= 1; off >>= 1) v += __shfl_xor(v, off);
    if ((threadIdx.x & 63) == 0) s[threadIdx.x >> 6] = v;
    __syncthreads();
    v = (s[0] + s[1]) + (s[2] + s[3]);
    __syncthreads();
    return v;
}

// ---------------- Kernel 2: per-column softmax + logclip sum ----------------
__global__ __launch_bounds__(256) void col_softmax_kernel(
    const float* __restrict__ z, float* __restrict__ colsum)
{
    const int sp = blockIdx.x;
    const int tid = threadIdx.x;
    const float* col = z + (size_t)sp * BATCH;

    float vals[8];
    float m = -3.4e38f;
#pragma unroll
    for (int i = 0; i < 8; ++i) {
        vals[i] = col[tid + 256 * i];
        m = fmaxf(m, vals[i]);
    }
    const float M = blk_reduce_max(m);

    float se = 0.0f;
#pragma unroll
    for (int i = 0; i < 8; ++i) se += __expf(vals[i] - M);
    const float S = blk_reduce_sum(se);
    const float L = __logf(S);

    float acc = 0.0f;
#pragma unroll
    for (int i = 0; i < 8; ++i) acc += fmaxf(vals[i] - M - L, LN_CLAMP);
    const float T = blk_reduce_sum(acc);
    if (tid == 0) colsum[sp] = T;
}

// ---------------- Kernel 3: final scalar ----------------
__global__ __launch_bounds__(256) void final_reduce_kernel(
    const float* __restrict__ colsum, float* __restrict__ out)
{
    const int tid = threadIdx.x;
    float v = 0.0f;
    for (int i = tid; i < SM1; i += 256) v += colsum[i];
    const float T = blk_reduce_sum(v);
    if (tid == 0) out[0] = T / (float)BATCH;
}

extern "C" void kernel_launch(void* const* d_in, const int* in_sizes, int n_in,
                              void* d_out, int out_size, void* d_ws, size_t ws_size,
                              hipStream_t stream) {
    const float* ys   = (const float*)d_in[0];
    const float* W1   = (const float*)d_in[1];
    const float* b1   = (const float*)d_in[2];
    const float* W2   = (const float*)d_in[3];
    const float* b2   = (const float*)d_in[4];
    const float* Wout = (const float*)d_in[5];
    const float* bout = (const float*)d_in[6];
    float* out = (float*)d_out;

    float* z      = (float*)d_ws;                         // SM1*BATCH floats
    float* colsum = z + (size_t)SM1 * BATCH;              // SM1 floats
    size_t fo = ((size_t)SM1 * BATCH + SM1) * sizeof(float);
    fo = (fo + 15) & ~(size_t)15;
    char* F = (char*)d_ws + fo;                           // 16*64*16 = 16 KB

    frag_setup_kernel<<<FRAG_UNITS, 64, 0, stream>>>(W1, b1, W2, b2, Wout, F);
    dim3 grid1(16, 64);  // 16*4 waves * 32 pts = 2048 b ; 64*16 = 1024 sp slots
    mlp_z_kernel<<<grid1, 256, 0, stream>>>(ys, F, bout, z);
    col_softmax_kernel<<<SM1, 256, 0, stream>>>(z, colsum);
    final_reduce_kernel<<<1, 256, 0, stream>>>(colsum, out);
}